// Round 10
// baseline (59.181 us; speedup 1.0000x reference)
//
#include <hip/hip_runtime.h>
#include <stdint.h>

#define BATCH  262144
#define HIST   100
#define HIDDEN 128
#define STAGE_F4 1600          // one stage: 32 rows x 50 float4 = 25.6 KB
#define RPB 128                // rows per block = 4 stages

typedef __attribute__((ext_vector_type(8))) short short8_t;  // 8 bf16
typedef __attribute__((ext_vector_type(4))) float f32x4;

__device__ __forceinline__ uint32_t cvt_pk_bf16(float lo, float hi) {
    uint32_t d;
    asm("v_cvt_pk_bf16_f32 %0, %1, %2" : "=v"(d) : "v"(lo), "v"(hi));
    return d;
}

union FragU { uint32_t u[4]; short8_t s8; uint4 u4; };

#define SBAR      __builtin_amdgcn_sched_barrier(0)
#define WAITV(n)  asm volatile("s_waitcnt vmcnt(" #n ")" ::: "memory")
#define WAITLGKM0 asm volatile("s_waitcnt lgkmcnt(0)" ::: "memory")

// stage stg (32 rows) -> LDS slot at tile[slotOff]: 25 x 1KB CONTIGUOUS
#define ISSUE(stg, slotOff)                                                   \
    _Pragma("unroll")                                                         \
    for (int i = 0; i < 25; ++i) {                                            \
        const float4* src = hist4 + slab + (stg) * STAGE_F4 + i * 64 + lane;  \
        __builtin_amdgcn_global_load_lds(                                     \
            (const __attribute__((address_space(1))) void*)src,               \
            (__attribute__((address_space(3))) void*)&tile[(slotOff) + i*64], \
            16, 0, 0);                                                        \
    }

// consume one 32-row stage from LDS: 2 lanes per row (q=lane&1), windows
// compile-time (idx=2c+q: early c<5, recent c>=20), pair shfl reduce.
__device__ __forceinline__ void consume_stage(
    const float4* __restrict__ slot, int rloc, int q,
    float& oS, float& oR, float& oM)
{
    float sum = 0.f, early = 0.f, recent = 0.f, maxd = 0.f;
    #pragma unroll
    for (int c = 0; c < 25; ++c) {
        float4 v = slot[rloc * 50 + 2 * c + q];
        float s2 = v.x + v.z;
        sum += s2;
        if (c < 5)   early  += s2;
        if (c >= 20) recent += s2;
        maxd = fmaxf(maxd, v.x > 0.5f ? v.y : 0.0f);
        maxd = fmaxf(maxd, v.z > 0.5f ? v.w : 0.0f);
    }
    float rme = recent - early;
    sum += __shfl_xor(sum, 1);
    rme += __shfl_xor(rme, 1);
    maxd = fmaxf(maxd, __shfl_xor(maxd, 1));
    oS = sum; oR = rme; oM = maxd;
}

// r7's proven MLP for 64 rows (lane=row): layer1 VALU + bf16 pack ->
// swizzled h1t -> MFMA 16x16x32 layer2 -> relu/W3/shfl-reduce epilogue.
__device__ __forceinline__ void mlp64(
    int lane, float f0, float f1, float f2, const short8_t bfr[8],
    const float* __restrict__ W1, const float* __restrict__ b1,
    float b2v0, float b2v1, float w3v0, float w3v1, float b3v,
    uint32_t* __restrict__ h1t, float* __restrict__ outBase)
{
    const int cl = lane & 15;
    const int ko = lane >> 4;
    const int r  = lane;

    f32x4 acc[4][2];
    #pragma unroll
    for (int g = 0; g < 4; ++g)
        #pragma unroll
        for (int n = 0; n < 2; ++n)
            acc[g][n] = (f32x4){0.f, 0.f, 0.f, 0.f};

    #pragma unroll
    for (int hh = 0; hh < 2; ++hh) {
        #pragma unroll
        for (int j8 = 0; j8 < 8; ++j8) {
            FragU pk;
            #pragma unroll
            for (int p = 0; p < 4; ++p) {
                const int j = hh * 64 + j8 * 8 + p * 2;
                float h0 = fmaf(f2, W1[256 + j],
                            fmaf(f1, W1[128 + j], fmaf(f0, W1[j], b1[j])));
                float h1 = fmaf(f2, W1[256 + j + 1],
                            fmaf(f1, W1[128 + j + 1],
                                 fmaf(f0, W1[j + 1], b1[j + 1])));
                pk.u[p] = cvt_pk_bf16(fmaxf(h0, 0.f), fmaxf(h1, 0.f));
            }
            *(uint4*)&h1t[r * 32 + ((j8 ^ (r & 7)) << 2)] = pk.u4;
        }
        #pragma unroll
        for (int g = 0; g < 4; ++g) {
            const int arow = g * 16 + cl;
            #pragma unroll
            for (int sp = 0; sp < 2; ++sp) {
                const int j8r = sp * 4 + ko;
                short8_t a = *(const short8_t*)
                    &h1t[arow * 32 + ((j8r ^ (arow & 7)) << 2)];
                const int s = hh * 2 + sp;
                acc[g][0] = __builtin_amdgcn_mfma_f32_16x16x32_bf16(
                    a, bfr[s * 2 + 0], acc[g][0], 0, 0, 0);
                acc[g][1] = __builtin_amdgcn_mfma_f32_16x16x32_bf16(
                    a, bfr[s * 2 + 1], acc[g][1], 0, 0, 0);
            }
        }
    }

    #pragma unroll
    for (int g = 0; g < 4; ++g) {
        float o[4];
        #pragma unroll
        for (int p = 0; p < 4; ++p) {
            float v0 = fmaxf(acc[g][0][p] + b2v0, 0.f) * w3v0;
            float v1 = fmaxf(acc[g][1][p] + b2v1, 0.f) * w3v1;
            o[p] = v0 + v1;
        }
        #pragma unroll
        for (int m = 1; m < 16; m <<= 1)
            #pragma unroll
            for (int p = 0; p < 4; ++p)
                o[p] += __shfl_xor(o[p], m);
        if (cl == 0) {
            float4 res;
            res.x = 1.f / (1.f + __expf(-(o[0] + b3v)));
            res.y = 1.f / (1.f + __expf(-(o[1] + b3v)));
            res.z = 1.f / (1.f + __expf(-(o[2] + b3v)));
            res.w = 1.f / (1.f + __expf(-(o[3] + b3v)));
            *(float4*)&outBase[g * 16 + ko * 4] = res;
        }
    }
}

// ONE WAVE per block, 128 rows = 4 contiguous-staged 32-row stages,
// 2 LDS slots ring-buffered with COUNTED vmcnt (never 0 mid-pipeline):
// 25-50KB of loads stay in flight through every consume; MLP pass0 runs
// under stages 2-3's streaming. h1t reuses consumed slots (no extra LDS).
// 51.2KB LDS -> 3 blocks/CU.
__global__ __launch_bounds__(64) void competence_kernel(
    const float* __restrict__ hist,
    const float* __restrict__ W1, const float* __restrict__ b1,
    const float* __restrict__ W2, const float* __restrict__ b2,
    const float* __restrict__ W3, const float* __restrict__ b3,
    float* __restrict__ out)
{
    __shared__ float4 tile[2 * STAGE_F4];   // 51.2 KB: slots A,B

    const int lane = threadIdx.x;
    const int rloc = lane >> 1;
    const int q    = lane & 1;
    const float4* __restrict__ hist4 = (const float4*)hist;
    const size_t slab = (size_t)blockIdx.x * (RPB * 50);

    // ---- issue stages 0,1 immediately (50 x 1KB in flight) ----
    ISSUE(0, 0)
    ISSUE(1, STAGE_F4)

    // ---- W2 -> bf16 B-fragments + scalar slices (hidden under streaming) --
    const int cl = lane & 15;
    const int ko = lane >> 4;
    const float b2v0 = b2[cl],  b2v1 = b2[16 + cl];
    const float w3v0 = W3[cl],  w3v1 = W3[16 + cl];
    const float b3v  = b3[0];

    short8_t bfr[8];
    #pragma unroll
    for (int s = 0; s < 4; ++s) {
        #pragma unroll
        for (int n = 0; n < 2; ++n) {
            float wv[8];
            #pragma unroll
            for (int i = 0; i < 8; ++i)
                wv[i] = W2[(32 * s + 8 * ko + i) * 32 + n * 16 + cl];
            FragU fu;
            #pragma unroll
            for (int p = 0; p < 4; ++p)
                fu.u[p] = cvt_pk_bf16(wv[2 * p], wv[2 * p + 1]);
            bfr[s * 2 + n] = fu.s8;
        }
    }

    float sumS[4], rmeS[4], maxS[4];

    WAITV(25); SBAR;
    consume_stage(tile, rloc, q, sumS[0], rmeS[0], maxS[0]);       // S0 @ A
    WAITLGKM0; SBAR;
    ISSUE(2, 0) SBAR;                                              // refill A
    WAITV(25); SBAR;
    consume_stage(tile + STAGE_F4, rloc, q, sumS[1], rmeS[1], maxS[1]); // S1 @ B

    // ---- MLP pass 0 (rows 0..63) while S2,S3 stream; h1t = slot B ----
    {
        const int src = (lane & 31) << 1;
        float sA = __shfl(sumS[0], src), sB = __shfl(sumS[1], src);
        float rA = __shfl(rmeS[0], src), rB = __shfl(rmeS[1], src);
        float mA = __shfl(maxS[0], src), mB = __shfl(maxS[1], src);
        const bool hi = lane >= 32;
        mlp64(lane, (hi ? sB : sA) * 0.01f, (hi ? rB : rA) * 0.05f,
              hi ? mB : mA, bfr, W1, b1, b2v0, b2v1, w3v0, w3v1, b3v,
              (uint32_t*)(tile + STAGE_F4),
              out + (size_t)blockIdx.x * RPB);
    }
    WAITLGKM0; SBAR;
    ISSUE(3, STAGE_F4) SBAR;                                       // refill B
    WAITV(25); SBAR;
    consume_stage(tile, rloc, q, sumS[2], rmeS[2], maxS[2]);       // S2 @ A
    WAITV(0); SBAR;
    consume_stage(tile + STAGE_F4, rloc, q, sumS[3], rmeS[3], maxS[3]); // S3 @ B

    // ---- MLP pass 1 (rows 64..127); h1t = slot A ----
    {
        const int src = (lane & 31) << 1;
        float sA = __shfl(sumS[2], src), sB = __shfl(sumS[3], src);
        float rA = __shfl(rmeS[2], src), rB = __shfl(rmeS[3], src);
        float mA = __shfl(maxS[2], src), mB = __shfl(maxS[3], src);
        const bool hi = lane >= 32;
        mlp64(lane, (hi ? sB : sA) * 0.01f, (hi ? rB : rA) * 0.05f,
              hi ? mB : mA, bfr, W1, b1, b2v0, b2v1, w3v0, w3v1, b3v,
              (uint32_t*)tile,
              out + (size_t)blockIdx.x * RPB + 64);
    }
}

extern "C" void kernel_launch(void* const* d_in, const int* in_sizes, int n_in,
                              void* d_out, int out_size, void* d_ws, size_t ws_size,
                              hipStream_t stream) {
    const float* hist = (const float*)d_in[0];
    const float* W1   = (const float*)d_in[1];
    const float* b1   = (const float*)d_in[2];
    const float* W2   = (const float*)d_in[3];
    const float* b2   = (const float*)d_in[4];
    const float* W3   = (const float*)d_in[5];
    const float* b3   = (const float*)d_in[6];
    float* out = (float*)d_out;

    const int threads = 64;            // one wave per block
    const int blocks  = BATCH / RPB;   // 2048 blocks
    competence_kernel<<<blocks, threads, 0, stream>>>(
        hist, W1, b1, W2, b2, W3, b3, out);
}

// Round 12
// 57.479 us; speedup vs baseline: 1.0296x; 1.0296x over previous
//
#include <hip/hip_runtime.h>
#include <stdint.h>

#define BATCH  262144
#define HIST   100
#define HIDDEN 128

typedef __attribute__((ext_vector_type(8))) short short8_t;  // 8 bf16
typedef __attribute__((ext_vector_type(4))) float f32x4;

__device__ __forceinline__ uint32_t cvt_pk_bf16(float lo, float hi) {
    uint32_t d;
    asm("v_cvt_pk_bf16_f32 %0, %1, %2" : "=v"(d) : "v"(lo), "v"(hi));
    return d;   // d[15:0]=bf16(lo), d[31:16]=bf16(hi)
}

union FragU { uint32_t u[4]; short8_t s8; uint4 u4; };

// r7 base (best: 41.6us) + NON-TEMPORAL history loads. Zero intra-dispatch
// reuse -> L2 insertion is pure overhead; nt = evict-first policy, testing
// whether the cache-insertion path is what caps reads at ~5.1 TB/s.
// NOTE: builtin requires a clang ext-vector pointer, not HIP_vector_type.
__device__ __forceinline__ f32x4 ldnt(const float* p) {
    return __builtin_nontemporal_load((const f32x4*)p);
}

// ONE WAVE per block (64 rows), 4096 blocks -> 16 independent wave-units
// per CU, free to drift (no __syncthreads anywhere).
//  1) stream: 4 lanes per row (full-line coalescing), NT loads,
//     4-lane shfl_xor butterfly, in-wave shfl redistribute (no LDS)
//  2) layer 1 on VALU, pack bf16, swizzled 8KB LDS tile (wave-local)
//  3) layer 2 on MFMA 16x16x32 bf16
//  4) epilogue: relu+b2, dot W3 via shfl reduce, sigmoid, float4 store
__global__ __launch_bounds__(64) void competence_kernel(
    const float* __restrict__ hist,
    const float* __restrict__ W1, const float* __restrict__ b1,
    const float* __restrict__ W2, const float* __restrict__ b2,
    const float* __restrict__ W3, const float* __restrict__ b3,
    float* __restrict__ out)
{
    __shared__ uint32_t h1t[2048];   // 8 KB: 64 rows x 32 dw, XOR-swizzled

    const int lane = threadIdx.x;    // 0..63
    const int q    = lane & 3;       // float4-phase within row
    const int rr   = lane >> 2;      // row within 16-row group
    const size_t row0 = (size_t)blockIdx.x * 64;

    // ---------------- phase 1: copy-class streaming (NT loads) ----------
    float fsum[4], frme[4], fmax[4];
    #pragma unroll
    for (int g = 0; g < 4; ++g) {
        const float* __restrict__ hrow =
            hist + (row0 + g * 16 + rr) * (HIST * 2);
        float sum = 0.f, early = 0.f, recent = 0.f, maxd = 0.f;
        #pragma unroll
        for (int i = 0; i < 12; ++i) {           // float4 idx = 4i+q in [0,48)
            f32x4 v = ldnt(hrow + (4 * i + q) * 4);
            float s2 = v.x + v.z;
            sum += s2;
            if (i < 2)       early += s2;                    // idx 0..7
            else if (i == 2) early += (q < 2) ? s2 : 0.f;    // idx 8,9 only
            if (i >= 10)     recent += s2;                   // idx 40..47
            maxd = fmaxf(maxd, v.x > 0.5f ? v.y : 0.0f);
            maxd = fmaxf(maxd, v.z > 0.5f ? v.w : 0.0f);
        }
        if (q < 2) {                             // tail: float4 idx 48,49
            f32x4 v = ldnt(hrow + (48 + q) * 4);
            float s2 = v.x + v.z;
            sum += s2; recent += s2;
            maxd = fmaxf(maxd, v.x > 0.5f ? v.y : 0.0f);
            maxd = fmaxf(maxd, v.z > 0.5f ? v.w : 0.0f);
        }
        float rme = recent - early;
        #pragma unroll
        for (int m = 1; m < 4; m <<= 1) {        // full butterfly: all 4 lanes
            sum += __shfl_xor(sum, m);
            rme += __shfl_xor(rme, m);
            maxd = fmaxf(maxd, __shfl_xor(maxd, m));
        }
        fsum[g] = sum; frme[g] = rme; fmax[g] = maxd;
    }

    // in-wave redistribute: thread `lane` = row g'*16+rr' needs group g'
    // triple from source lane 4*rr' (butterfly left it in all 4 lanes)
    const int src  = (lane & 15) << 2;
    const int gsel = lane >> 4;
    float s0 = __shfl(fsum[0], src), s1 = __shfl(fsum[1], src),
          s2 = __shfl(fsum[2], src), s3 = __shfl(fsum[3], src);
    float r0 = __shfl(frme[0], src), r1 = __shfl(frme[1], src),
          r2 = __shfl(frme[2], src), r3 = __shfl(frme[3], src);
    float m0 = __shfl(fmax[0], src), m1 = __shfl(fmax[1], src),
          m2 = __shfl(fmax[2], src), m3 = __shfl(fmax[3], src);
    const float f0 = ((gsel & 2) ? ((gsel & 1) ? s3 : s2)
                                 : ((gsel & 1) ? s1 : s0)) * 0.01f;
    const float f1 = ((gsel & 2) ? ((gsel & 1) ? r3 : r2)
                                 : ((gsel & 1) ? r1 : r0)) * 0.05f;
    const float f2 =  (gsel & 2) ? ((gsel & 1) ? m3 : m2)
                                 : ((gsel & 1) ? m1 : m0);

    // ---------------- B fragments (W2 -> bf16) + per-lane b2/W3 slices -----
    const int cl = lane & 15;
    const int ko = lane >> 4;
    const float b2v0 = b2[cl],  b2v1 = b2[16 + cl];
    const float w3v0 = W3[cl],  w3v1 = W3[16 + cl];
    const float b3v  = b3[0];

    short8_t bfr[8];                             // [kstep s][ntile n] = s*2+n
    #pragma unroll
    for (int s = 0; s < 4; ++s) {
        #pragma unroll
        for (int n = 0; n < 2; ++n) {
            float wv[8];
            #pragma unroll
            for (int i = 0; i < 8; ++i)          // k = 32s + 8*ko + i
                wv[i] = W2[(32 * s + 8 * ko + i) * 32 + n * 16 + cl];
            FragU fu;
            #pragma unroll
            for (int p = 0; p < 4; ++p)
                fu.u[p] = cvt_pk_bf16(wv[2 * p], wv[2 * p + 1]);
            bfr[s * 2 + n] = fu.s8;
        }
    }

    f32x4 acc[4][2];
    #pragma unroll
    for (int g = 0; g < 4; ++g)
        #pragma unroll
        for (int n = 0; n < 2; ++n)
            acc[g][n] = (f32x4){0.f, 0.f, 0.f, 0.f};

    const int r = lane;

    #pragma unroll
    for (int hh = 0; hh < 2; ++hh) {             // K halves: j in [64hh,64hh+64)
        // ---- layer 1 for this half: compute, pack, swizzled LDS write ----
        #pragma unroll
        for (int j8 = 0; j8 < 8; ++j8) {
            FragU pk;
            #pragma unroll
            for (int p = 0; p < 4; ++p) {
                const int j = hh * 64 + j8 * 8 + p * 2;
                float h0 = fmaf(f2, W1[256 + j],
                            fmaf(f1, W1[128 + j], fmaf(f0, W1[j], b1[j])));
                float h1 = fmaf(f2, W1[256 + j + 1],
                            fmaf(f1, W1[128 + j + 1],
                                 fmaf(f0, W1[j + 1], b1[j + 1])));
                pk.u[p] = cvt_pk_bf16(fmaxf(h0, 0.f), fmaxf(h1, 0.f));
            }
            *(uint4*)&h1t[r * 32 + ((j8 ^ (r & 7)) << 2)] = pk.u4;
        }
        // ---- MFMA for this half (wave-local LDS, no barrier needed) ----
        #pragma unroll
        for (int g = 0; g < 4; ++g) {
            const int arow = g * 16 + cl;
            #pragma unroll
            for (int sp = 0; sp < 2; ++sp) {
                const int j8r = sp * 4 + ko;
                short8_t a = *(const short8_t*)
                    &h1t[arow * 32 + ((j8r ^ (arow & 7)) << 2)];
                const int s = hh * 2 + sp;
                acc[g][0] = __builtin_amdgcn_mfma_f32_16x16x32_bf16(
                    a, bfr[s * 2 + 0], acc[g][0], 0, 0, 0);
                acc[g][1] = __builtin_amdgcn_mfma_f32_16x16x32_bf16(
                    a, bfr[s * 2 + 1], acc[g][1], 0, 0, 0);
            }
        }
    }

    // ---------------- epilogue ----------------
    #pragma unroll
    for (int g = 0; g < 4; ++g) {
        float o[4];
        #pragma unroll
        for (int p = 0; p < 4; ++p) {
            float v0 = fmaxf(acc[g][0][p] + b2v0, 0.f) * w3v0;
            float v1 = fmaxf(acc[g][1][p] + b2v1, 0.f) * w3v1;
            o[p] = v0 + v1;
        }
        #pragma unroll
        for (int m = 1; m < 16; m <<= 1)
            #pragma unroll
            for (int p = 0; p < 4; ++p)
                o[p] += __shfl_xor(o[p], m);
        if (cl == 0) {
            float4 res;
            res.x = 1.f / (1.f + __expf(-(o[0] + b3v)));
            res.y = 1.f / (1.f + __expf(-(o[1] + b3v)));
            res.z = 1.f / (1.f + __expf(-(o[2] + b3v)));
            res.w = 1.f / (1.f + __expf(-(o[3] + b3v)));
            *(float4*)&out[blockIdx.x * 64 + g * 16 + ko * 4] = res;
        }
    }
}

extern "C" void kernel_launch(void* const* d_in, const int* in_sizes, int n_in,
                              void* d_out, int out_size, void* d_ws, size_t ws_size,
                              hipStream_t stream) {
    const float* hist = (const float*)d_in[0];
    const float* W1   = (const float*)d_in[1];
    const float* b1   = (const float*)d_in[2];
    const float* W2   = (const float*)d_in[3];
    const float* b2   = (const float*)d_in[4];
    const float* W3   = (const float*)d_in[5];
    const float* b3   = (const float*)d_in[6];
    float* out = (float*)d_out;

    const int threads = 64;            // one wave per block
    const int blocks  = BATCH / 64;    // 4096 blocks -> 16 wave-units/CU
    competence_kernel<<<blocks, threads, 0, stream>>>(
        hist, W1, b1, W2, b2, W3, b3, out);
}

// Round 13
// 41.477 us; speedup vs baseline: 1.4268x; 1.3858x over previous
//
#include <hip/hip_runtime.h>
#include <stdint.h>

#define BATCH  262144
#define HIST   100
#define HIDDEN 128

typedef __attribute__((ext_vector_type(8))) short short8_t;  // 8 bf16
typedef __attribute__((ext_vector_type(4))) float f32x4;

__device__ __forceinline__ uint32_t cvt_pk_bf16(float lo, float hi) {
    uint32_t d;
    asm("v_cvt_pk_bf16_f32 %0, %1, %2" : "=v"(d) : "v"(lo), "v"(hi));
    return d;   // d[15:0]=bf16(lo), d[31:16]=bf16(hi)
}

union FragU { uint32_t u[4]; short8_t s8; uint4 u4; };

// REVERT to r7 (best verified: 41.6us, 5.07 TB/s effective).
// r12's non-temporal variant regressed to 57.5us -> caches were helping;
// read path is not insertion-limited. Six streaming structures all pin
// at ~5.0-5.1 TB/s: this is the access-class ceiling, not a kernel flaw.
//
// ONE WAVE per block (64 rows), 4096 blocks -> 16 independent wave-units
// per CU, free to drift (no __syncthreads anywhere).
//  1) stream: 4 lanes per row (full-line coalescing),
//     4-lane shfl_xor butterfly, in-wave shfl redistribute (no LDS)
//  2) layer 1 on VALU, pack bf16, swizzled 8KB LDS tile (wave-local)
//  3) layer 2 on MFMA 16x16x32 bf16
//  4) epilogue: relu+b2, dot W3 via shfl reduce, sigmoid, float4 store
__global__ __launch_bounds__(64) void competence_kernel(
    const float* __restrict__ hist,
    const float* __restrict__ W1, const float* __restrict__ b1,
    const float* __restrict__ W2, const float* __restrict__ b2,
    const float* __restrict__ W3, const float* __restrict__ b3,
    float* __restrict__ out)
{
    __shared__ uint32_t h1t[2048];   // 8 KB: 64 rows x 32 dw, XOR-swizzled

    const int lane = threadIdx.x;    // 0..63
    const int q    = lane & 3;       // float4-phase within row
    const int rr   = lane >> 2;      // row within 16-row group
    const size_t row0 = (size_t)blockIdx.x * 64;

    // ---------------- phase 1: copy-class streaming ----------------
    float fsum[4], frme[4], fmax[4];
    #pragma unroll
    for (int g = 0; g < 4; ++g) {
        const float4* __restrict__ h4 =
            (const float4*)(hist + (row0 + g * 16 + rr) * (HIST * 2));
        float sum = 0.f, early = 0.f, recent = 0.f, maxd = 0.f;
        #pragma unroll
        for (int i = 0; i < 12; ++i) {           // float4 idx = 4i+q in [0,48)
            float4 v = h4[4 * i + q];
            float s2 = v.x + v.z;
            sum += s2;
            if (i < 2)       early += s2;                    // idx 0..7
            else if (i == 2) early += (q < 2) ? s2 : 0.f;    // idx 8,9 only
            if (i >= 10)     recent += s2;                   // idx 40..47
            maxd = fmaxf(maxd, v.x > 0.5f ? v.y : 0.0f);
            maxd = fmaxf(maxd, v.z > 0.5f ? v.w : 0.0f);
        }
        if (q < 2) {                             // tail: float4 idx 48,49
            float4 v = h4[48 + q];
            float s2 = v.x + v.z;
            sum += s2; recent += s2;
            maxd = fmaxf(maxd, v.x > 0.5f ? v.y : 0.0f);
            maxd = fmaxf(maxd, v.z > 0.5f ? v.w : 0.0f);
        }
        float rme = recent - early;
        #pragma unroll
        for (int m = 1; m < 4; m <<= 1) {        // full butterfly: all 4 lanes
            sum += __shfl_xor(sum, m);
            rme += __shfl_xor(rme, m);
            maxd = fmaxf(maxd, __shfl_xor(maxd, m));
        }
        fsum[g] = sum; frme[g] = rme; fmax[g] = maxd;
    }

    // in-wave redistribute: thread `lane` = row g'*16+rr' needs group g'
    // triple from source lane 4*rr' (butterfly left it in all 4 lanes)
    const int src  = (lane & 15) << 2;
    const int gsel = lane >> 4;
    float s0 = __shfl(fsum[0], src), s1 = __shfl(fsum[1], src),
          s2 = __shfl(fsum[2], src), s3 = __shfl(fsum[3], src);
    float r0 = __shfl(frme[0], src), r1 = __shfl(frme[1], src),
          r2 = __shfl(frme[2], src), r3 = __shfl(frme[3], src);
    float m0 = __shfl(fmax[0], src), m1 = __shfl(fmax[1], src),
          m2 = __shfl(fmax[2], src), m3 = __shfl(fmax[3], src);
    const float f0 = ((gsel & 2) ? ((gsel & 1) ? s3 : s2)
                                 : ((gsel & 1) ? s1 : s0)) * 0.01f;
    const float f1 = ((gsel & 2) ? ((gsel & 1) ? r3 : r2)
                                 : ((gsel & 1) ? r1 : r0)) * 0.05f;
    const float f2 =  (gsel & 2) ? ((gsel & 1) ? m3 : m2)
                                 : ((gsel & 1) ? m1 : m0);

    // ---------------- B fragments (W2 -> bf16) + per-lane b2/W3 slices -----
    const int cl = lane & 15;
    const int ko = lane >> 4;
    const float b2v0 = b2[cl],  b2v1 = b2[16 + cl];
    const float w3v0 = W3[cl],  w3v1 = W3[16 + cl];
    const float b3v  = b3[0];

    short8_t bfr[8];                             // [kstep s][ntile n] = s*2+n
    #pragma unroll
    for (int s = 0; s < 4; ++s) {
        #pragma unroll
        for (int n = 0; n < 2; ++n) {
            float wv[8];
            #pragma unroll
            for (int i = 0; i < 8; ++i)          // k = 32s + 8*ko + i
                wv[i] = W2[(32 * s + 8 * ko + i) * 32 + n * 16 + cl];
            FragU fu;
            #pragma unroll
            for (int p = 0; p < 4; ++p)
                fu.u[p] = cvt_pk_bf16(wv[2 * p], wv[2 * p + 1]);
            bfr[s * 2 + n] = fu.s8;
        }
    }

    f32x4 acc[4][2];
    #pragma unroll
    for (int g = 0; g < 4; ++g)
        #pragma unroll
        for (int n = 0; n < 2; ++n)
            acc[g][n] = (f32x4){0.f, 0.f, 0.f, 0.f};

    const int r = lane;

    #pragma unroll
    for (int hh = 0; hh < 2; ++hh) {             // K halves: j in [64hh,64hh+64)
        // ---- layer 1 for this half: compute, pack, swizzled LDS write ----
        #pragma unroll
        for (int j8 = 0; j8 < 8; ++j8) {
            FragU pk;
            #pragma unroll
            for (int p = 0; p < 4; ++p) {
                const int j = hh * 64 + j8 * 8 + p * 2;
                float h0 = fmaf(f2, W1[256 + j],
                            fmaf(f1, W1[128 + j], fmaf(f0, W1[j], b1[j])));
                float h1 = fmaf(f2, W1[256 + j + 1],
                            fmaf(f1, W1[128 + j + 1],
                                 fmaf(f0, W1[j + 1], b1[j + 1])));
                pk.u[p] = cvt_pk_bf16(fmaxf(h0, 0.f), fmaxf(h1, 0.f));
            }
            *(uint4*)&h1t[r * 32 + ((j8 ^ (r & 7)) << 2)] = pk.u4;
        }
        // ---- MFMA for this half (wave-local LDS, no barrier needed) ----
        #pragma unroll
        for (int g = 0; g < 4; ++g) {
            const int arow = g * 16 + cl;
            #pragma unroll
            for (int sp = 0; sp < 2; ++sp) {
                const int j8r = sp * 4 + ko;
                short8_t a = *(const short8_t*)
                    &h1t[arow * 32 + ((j8r ^ (arow & 7)) << 2)];
                const int s = hh * 2 + sp;
                acc[g][0] = __builtin_amdgcn_mfma_f32_16x16x32_bf16(
                    a, bfr[s * 2 + 0], acc[g][0], 0, 0, 0);
                acc[g][1] = __builtin_amdgcn_mfma_f32_16x16x32_bf16(
                    a, bfr[s * 2 + 1], acc[g][1], 0, 0, 0);
            }
        }
    }

    // ---------------- epilogue ----------------
    #pragma unroll
    for (int g = 0; g < 4; ++g) {
        float o[4];
        #pragma unroll
        for (int p = 0; p < 4; ++p) {
            float v0 = fmaxf(acc[g][0][p] + b2v0, 0.f) * w3v0;
            float v1 = fmaxf(acc[g][1][p] + b2v1, 0.f) * w3v1;
            o[p] = v0 + v1;
        }
        #pragma unroll
        for (int m = 1; m < 16; m <<= 1)
            #pragma unroll
            for (int p = 0; p < 4; ++p)
                o[p] += __shfl_xor(o[p], m);
        if (cl == 0) {
            float4 res;
            res.x = 1.f / (1.f + __expf(-(o[0] + b3v)));
            res.y = 1.f / (1.f + __expf(-(o[1] + b3v)));
            res.z = 1.f / (1.f + __expf(-(o[2] + b3v)));
            res.w = 1.f / (1.f + __expf(-(o[3] + b3v)));
            *(float4*)&out[blockIdx.x * 64 + g * 16 + ko * 4] = res;
        }
    }
}

extern "C" void kernel_launch(void* const* d_in, const int* in_sizes, int n_in,
                              void* d_out, int out_size, void* d_ws, size_t ws_size,
                              hipStream_t stream) {
    const float* hist = (const float*)d_in[0];
    const float* W1   = (const float*)d_in[1];
    const float* b1   = (const float*)d_in[2];
    const float* W2   = (const float*)d_in[3];
    const float* b2   = (const float*)d_in[4];
    const float* W3   = (const float*)d_in[5];
    const float* b3   = (const float*)d_in[6];
    float* out = (float*)d_out;

    const int threads = 64;            // one wave per block
    const int blocks  = BATCH / 64;    // 4096 blocks -> 16 wave-units/CU
    competence_kernel<<<blocks, threads, 0, stream>>>(
        hist, W1, b1, W2, b2, W3, b3, out);
}